// Round 10
// baseline (164.905 us; speedup 1.0000x reference)
//
#include <hip/hip_runtime.h>
#include <hip/hip_bf16.h>

typedef unsigned short u16;
typedef unsigned int u32;
typedef __attribute__((ext_vector_type(8))) __bf16 bf16x8;
typedef __attribute__((ext_vector_type(4))) __bf16 bf16x4;
typedef __attribute__((ext_vector_type(4))) float f32x4;
typedef __attribute__((ext_vector_type(2))) float f32x2;
typedef __attribute__((ext_vector_type(4))) u32 u32x4;

#define KCTX 32
#define INF_ 608
#define HID_ 384
#define NBOX 16384
#define WSTR 512                      // Whp row stride (u16): 8 slices x 64

// ws layout (bytes).
#define WHP_OFF  0                    // Whp [16384,512] bf16 = 16,777,216
#define BT_OFF   16777216             // Bt  [384,608]  bf16 =    466,944
#define V_OFF    17244160             // v   [608] f32        =      2,432
#define SI_OFF   17246592             // si  [16384] f32      =     65,536
#define SJ_OFF   17312128             // sj  [16384] f32      =     65,536
#define AJF_OFF  17377664             // ajf [384] f32        =      1,536
#define ABF_OFF  17379200             // abf f32 (+pad)
#define ATTP_OFF 17379264             // attp [16384,32] f32x2 = 4,194,304

__device__ __forceinline__ float bfu(u16 u)  { return __uint_as_float(((u32)u) << 16); }
__device__ __forceinline__ float bflo(u32 u) { return __uint_as_float(u << 16); }
__device__ __forceinline__ float bfhi(u32 u) { return __uint_as_float(u & 0xffff0000u); }
__device__ __forceinline__ u16 f2bf(float x) {            // round-to-nearest-even
  u32 u = __float_as_uint(x);
  return (u16)((u + 0x7fffu + ((u >> 16) & 1u)) >> 16);
}
__device__ __forceinline__ void async_ld16(const void* g, void* l) {
  __builtin_amdgcn_global_load_lds(
      (const __attribute__((address_space(1))) u32*)g,
      (__attribute__((address_space(3))) u32*)l, 16, 0, 0);
}

// ---- per-wave runtime dtype detection (wave-uniform, L2-hot; validated r2-r9) ----
__device__ __forceinline__ int detect_f32(const u32* hw) {
  const u32 w = hw[threadIdx.x & 63];
  const int e = (int)((w >> 7) & 0xffu);
  const unsigned long long mb = __ballot(e > 134 || e < 100);
  return __popcll(mb) >= 16;
}
__device__ __forceinline__ int detect_i64(const int* ci) {
  const int hi = ci[2 * (threadIdx.x & 63) + 1];
  const unsigned long long mz = __ballot(hi == 0 || hi == -1);
  return __popcll(mz) >= 48;
}

// ---- prep: Bt = bf16(W_j^T), v = W_i@a_i, ajf/abf fp32, zero sj (unchanged) ----
__global__ __launch_bounds__(256) void prep_kernel(
    const void* __restrict__ h, const void* __restrict__ Wi,
    const void* __restrict__ Wj, const void* __restrict__ ai,
    const void* __restrict__ aj, const void* __restrict__ ab,
    u16* __restrict__ Bt, float* __restrict__ v, float* __restrict__ sj,
    float* __restrict__ ajf, float* __restrict__ abf) {
  __shared__ u16 tile[64][65];
  const int f32m = detect_f32((const u32*)h);
  const int bid = blockIdx.x, tid = threadIdx.x;
  if (bid < 60) {
    const int ft = bid / 6, ht = bid - ft * 6;
    const int f0 = ft * 64, h0 = ht * 64;
    const int ln = tid & 63, fg = tid >> 6;
#pragma unroll
    for (int rr = 0; rr < 16; ++rr) {
      const int fl = fg * 16 + rr;
      const int f = f0 + fl;
      if (f < INF_)
        tile[fl][ln] = f32m ? f2bf(((const float*)Wj)[(size_t)f * HID_ + h0 + ln])
                            : ((const u16*)Wj)[(size_t)f * HID_ + h0 + ln];
    }
    __syncthreads();
#pragma unroll
    for (int rr = 0; rr < 16; ++rr) {
      const int hl = fg * 16 + rr;
      const int f = f0 + ln;
      if (f < INF_) Bt[(size_t)(h0 + hl) * INF_ + f] = tile[ln][hl];
    }
  } else if (bid < 98) {
    const int t = (bid - 60) * 16 + (tid >> 4);
    const int sl = tid & 15;
    if (t < INF_) {
      float s = 0.f;
      if (f32m) {
        const float4* wi = (const float4*)((const float*)Wi + (size_t)t * HID_);
        const float4* a4 = (const float4*)ai;
        for (int c = sl; c < 96; c += 16) {
          float4 x = wi[c], y = a4[c];
          s += x.x * y.x + x.y * y.y + x.z * y.z + x.w * y.w;
        }
      } else {
        const uint4* wi = (const uint4*)((const u16*)Wi + (size_t)t * HID_);
        const uint4* a4 = (const uint4*)ai;
        for (int c = sl; c < 48; c += 16) {
          uint4 x = wi[c], y = a4[c];
          s += bflo(x.x) * bflo(y.x) + bfhi(x.x) * bfhi(y.x)
             + bflo(x.y) * bflo(y.y) + bfhi(x.y) * bfhi(y.y)
             + bflo(x.z) * bflo(y.z) + bfhi(x.z) * bfhi(y.z)
             + bflo(x.w) * bflo(y.w) + bfhi(x.w) * bfhi(y.w);
        }
      }
      s += __shfl_xor(s, 1); s += __shfl_xor(s, 2);
      s += __shfl_xor(s, 4); s += __shfl_xor(s, 8);
      if (sl == 0) v[t] = s;
    }
  } else {
#pragma unroll 8
    for (int j = 0; j < 64; ++j) sj[j * 256 + tid] = 0.f;
    for (int j = tid; j < HID_; j += 256)
      ajf[j] = f32m ? ((const float*)aj)[j] : bfu(((const u16*)aj)[j]);
    if (tid == 0)
      abf[0] = f32m ? ((const float*)ab)[0] : bfu(((const u16*)ab)[0]);
  }
}

// ---- gemm_fused (r8 core): writes C into sliced-padded Whp layout ----
__global__ __launch_bounds__(256) void gemm_fused(
    const void* __restrict__ A, const u16* __restrict__ Bt,
    const float* __restrict__ v, u16* __restrict__ C,   // C = Whp stride 512
    float* __restrict__ si, const float* __restrict__ ajf,
    float* __restrict__ sj) {
  __shared__ __align__(16) u16 As[32][612];
  __shared__ __align__(16) u16 Bs[12288];          // [384][32]
  const int f32m = detect_f32((const u32*)A);
  const int tid  = threadIdx.x;
  const int lane = tid & 63;
  const int wv   = tid >> 6;
  const int row0 = blockIdx.x * 32;
  const char* Btb = (const char*)Bt;

#pragma unroll
  for (int i = 0; i < 6; ++i) {
    const int c = tid + i * 256;
    async_ld16(Btb + (size_t)(c >> 2) * 1216 + (c & 3) * 16, (char*)Bs + c * 16);
  }

  {
    const int g = tid >> 3, sub = tid & 7;
    float s = 0.f;
    const float4* v4 = (const float4*)v;
    if (f32m) {
      const float4* hr = (const float4*)((const float*)A + (size_t)(row0 + g) * INF_);
#pragma unroll
      for (int k = 0; k < 19; ++k) {
        const int c4 = sub + 8 * k;
        float4 x = hr[c4];
        ushort4 sv;
        sv.x = f2bf(x.x); sv.y = f2bf(x.y); sv.z = f2bf(x.z); sv.w = f2bf(x.w);
        *(ushort4*)&As[g][c4 * 4] = sv;
        float4 w = v4[c4];
        s += x.x * w.x + x.y * w.y + x.z * w.z + x.w * w.w;
      }
    } else {
      const uint4* hr = (const uint4*)((const u16*)A + (size_t)(row0 + g) * INF_);
      for (int k = 0; k < 10; ++k) {
        const int c8 = sub + 8 * k;
        if (c8 < 76) {
          uint4 x = hr[c8];
          *(ushort4*)&As[g][c8 * 8]     = *(ushort4*)&x.x;
          *(ushort4*)&As[g][c8 * 8 + 4] = *(ushort4*)&x.z;
          float4 w0 = v4[2 * c8], w1 = v4[2 * c8 + 1];
          s += bflo(x.x) * w0.x + bfhi(x.x) * w0.y + bflo(x.y) * w0.z + bfhi(x.y) * w0.w
             + bflo(x.z) * w1.x + bfhi(x.z) * w1.y + bflo(x.w) * w1.z + bfhi(x.w) * w1.w;
        }
      }
    }
    s += __shfl_xor(s, 1); s += __shfl_xor(s, 2); s += __shfl_xor(s, 4);
    if (sub == 0) si[row0 + g] = s;
  }

  f32x4 acc[2][6];
#pragma unroll
  for (int i = 0; i < 2; ++i)
#pragma unroll
    for (int j = 0; j < 6; ++j) acc[i][j] = (f32x4){0.f, 0.f, 0.f, 0.f};

  const int lm = lane & 15, q = lane >> 4;
  const int n0 = wv * 96;

  for (int kt = 0; kt < 19; ++kt) {
    __syncthreads();
    bf16x8 af[2], bfr[6];
#pragma unroll
    for (int im = 0; im < 2; ++im) {
      const int r = im * 16 + lm;
      bf16x4 lo = *(const bf16x4*)&As[r][kt * 32 + q * 8];
      bf16x4 hi = *(const bf16x4*)&As[r][kt * 32 + q * 8 + 4];
      af[im] = __builtin_shufflevector(lo, hi, 0, 1, 2, 3, 4, 5, 6, 7);
    }
#pragma unroll
    for (int in = 0; in < 6; ++in)
      bfr[in] = *(const bf16x8*)&Bs[(n0 + in * 16 + lm) * 32 + q * 8];
#pragma unroll
    for (int im = 0; im < 2; ++im)
#pragma unroll
      for (int in = 0; in < 6; ++in)
        acc[im][in] = __builtin_amdgcn_mfma_f32_16x16x32_bf16(
            af[im], bfr[in], acc[im][in], 0, 0, 0);
    __syncthreads();
    if (kt < 18) {
      const size_t kb = (size_t)(kt + 1) * 64;
#pragma unroll
      for (int i = 0; i < 6; ++i) {
        const int c = tid + i * 256;
        async_ld16(Btb + (size_t)(c >> 2) * 1216 + kb + (c & 3) * 16, (char*)Bs + c * 16);
      }
    }
  }

  // epilogue: store into sliced layout (slice = col/48, 64-u16 stride per slice)
#pragma unroll
  for (int im = 0; im < 2; ++im)
#pragma unroll
    for (int in = 0; in < 6; ++in) {
      const int cb = in * 16 + lm;                 // 0..95 in wave band (lm<16, 48=3*16)
      const int slc = wv * 2 + (in >= 3 ? 1 : 0);  // 0..7
      const int cc  = cb - (in >= 3 ? 48 : 0);     // 0..47
#pragma unroll
      for (int r = 0; r < 4; ++r) {
        const int rowg = row0 + im * 16 + q * 4 + r;
        C[(size_t)rowg * WSTR + slc * 64 + cc] = f2bf(acc[im][in][r]);
      }
    }
  float ajv[6];
#pragma unroll
  for (int in = 0; in < 6; ++in) ajv[in] = ajf[n0 + in * 16 + lm];
#pragma unroll
  for (int im = 0; im < 2; ++im)
#pragma unroll
    for (int r = 0; r < 4; ++r) {
      float p = acc[im][0][r] * ajv[0] + acc[im][1][r] * ajv[1]
              + acc[im][2][r] * ajv[2] + acc[im][3][r] * ajv[3]
              + acc[im][4][r] * ajv[4] + acc[im][5][r] * ajv[5];
      p += __shfl_xor(p, 1); p += __shfl_xor(p, 2);
      p += __shfl_xor(p, 4); p += __shfl_xor(p, 8);
      if (lm == 0) atomicAdd(&sj[row0 + im * 16 + q * 4 + r], p);
    }
}

// ---- score: softmax weights once -> packed (att, idx) [NT store] ----
__global__ __launch_bounds__(256) void score_kernel(
    const int* __restrict__ ci, const float* __restrict__ si,
    const float* __restrict__ sj, const float* __restrict__ abf,
    f32x2* __restrict__ attp) {
  const int i64 = detect_i64(ci);
  const int r = threadIdx.x >> 5, k = threadIdx.x & 31;
  const int n = blockIdx.x * 8 + r;
  const size_t t = (size_t)n * KCTX + k;
  int idx;
  if (i64) { int lo = ci[2 * t], hi = ci[2 * t + 1]; idx = (hi < 0) ? -1 : lo; }
  else     { idx = ci[t]; }
  const bool valid = idx >= 0;
  const float sjv = valid ? sj[idx] : 0.f;
  float raw = si[n] + sjv + abf[0];
  float lr = raw > 0.f ? raw : 0.2f * raw;
  float s = valid ? lr : -9e15f;
  float m = s;
#pragma unroll
  for (int o = 16; o; o >>= 1) m = fmaxf(m, __shfl_xor(m, o, 32));
  float p = __expf(s - m);
  float d = p;
#pragma unroll
  for (int o = 16; o; o >>= 1) d += __shfl_xor(d, o, 32);
  f32x2 e;
  e.x = valid ? p / d : 0.f;
  e.y = __int_as_float(valid ? idx : 0);
  __builtin_nontemporal_store(e, &attp[t]);
}

// ---- attn: XCD-affine slice gather. slice = blockIdx&7 (one 2.1 MB slice
// per XCD L2); 40 rows/block; wave = 10 rows x 6 x 16B chunks (60 lanes);
// attp in via NT loads, out via NT stores (no L2 pollution of the slice). ----
__global__ __launch_bounds__(256) void attn_kernel(
    const void* __restrict__ h, const f32x2* __restrict__ attp,
    const u16* __restrict__ Whp, void* __restrict__ out) {
  __shared__ f32x2 att_s[40][33];                  // +1 pad: conflict-free reads
  const int f32m = detect_f32((const u32*)h);
  const int tid = threadIdx.x;
  const int slc = blockIdx.x & 7;
  const int n0 = (blockIdx.x >> 3) * 40;

  // stage (att, idx) for 40 rows (NT: bypass L2)
#pragma unroll
  for (int i = 0; i < 5; ++i) {
    const int e = tid + i * 256;                   // 0..1279
    const int rr = e >> 5, kk = e & 31;
    f32x2 val = (f32x2){0.f, 0.f};
    if (n0 + rr < NBOX)
      val = __builtin_nontemporal_load(&attp[(size_t)n0 * KCTX + e]);
    att_s[rr][kk] = val;
  }
  __syncthreads();

  const int wv = tid >> 6, lane = tid & 63;
  if (lane < 60) {
    const int rr = lane / 6, cc = lane - rr * 6;   // 10 rows x 6 chunks
    const int lr = wv * 10 + rr;                   // 0..39
    const int n = n0 + lr;
    const u16* base = Whp + slc * 64 + cc * 8;
    float a0 = 0, a1 = 0, a2 = 0, a3 = 0, a4 = 0, a5 = 0, a6 = 0, a7 = 0;
#pragma unroll
    for (int kb = 0; kb < KCTX; kb += 8) {
      uint4 q[8]; float ww[8];
#pragma unroll
      for (int u = 0; u < 8; ++u) {                // 8 loads in flight
        const f32x2 e = att_s[lr][kb + u];
        ww[u] = e.x;
        const u32 j = (u32)__float_as_int(e.y);
        q[u] = *(const uint4*)(base + (size_t)j * WSTR);
      }
#pragma unroll
      for (int u = 0; u < 8; ++u) {
        const float w = ww[u];
        a0 += w * bflo(q[u].x); a1 += w * bfhi(q[u].x);
        a2 += w * bflo(q[u].y); a3 += w * bfhi(q[u].y);
        a4 += w * bflo(q[u].z); a5 += w * bfhi(q[u].z);
        a6 += w * bflo(q[u].w); a7 += w * bfhi(q[u].w);
      }
    }
    if (n < NBOX) {
      const int c0 = slc * 48 + cc * 8;            // output col base
      if (f32m) {
        float* op = (float*)out + (size_t)n * HID_ + c0;
        __builtin_nontemporal_store((f32x4){a0, a1, a2, a3}, (f32x4*)op);
        __builtin_nontemporal_store((f32x4){a4, a5, a6, a7}, (f32x4*)(op + 4));
      } else {
        u32x4 o;
        o.x = (u32)f2bf(a0) | ((u32)f2bf(a1) << 16);
        o.y = (u32)f2bf(a2) | ((u32)f2bf(a3) << 16);
        o.z = (u32)f2bf(a4) | ((u32)f2bf(a5) << 16);
        o.w = (u32)f2bf(a6) | ((u32)f2bf(a7) << 16);
        __builtin_nontemporal_store(o, (u32x4*)((u16*)out + (size_t)n * HID_ + c0));
      }
    }
  }
}

extern "C" void kernel_launch(void* const* d_in, const int* in_sizes, int n_in,
                              void* d_out, int out_size, void* d_ws, size_t ws_size,
                              hipStream_t stream) {
  const void* h  = d_in[0];
  const int*  ci = (const int*)d_in[1];
  const void* Wi = d_in[2];
  const void* Wj = d_in[3];
  const void* ai = d_in[4];
  const void* aj = d_in[5];
  const void* ab = d_in[6];

  char* ws = (char*)d_ws;
  u16*   Whp  = (u16*)(ws + WHP_OFF);
  u16*   Bt   = (u16*)(ws + BT_OFF);
  float* v    = (float*)(ws + V_OFF);
  float* si   = (float*)(ws + SI_OFF);
  float* sj   = (float*)(ws + SJ_OFF);
  float* ajf  = (float*)(ws + AJF_OFF);
  float* abf  = (float*)(ws + ABF_OFF);
  f32x2* attp = (f32x2*)(ws + ATTP_OFF);

  prep_kernel<<<99, 256, 0, stream>>>(h, Wi, Wj, ai, aj, ab, Bt, v, sj, ajf, abf);
  gemm_fused<<<512, 256, 0, stream>>>(h, Bt, v, Whp, si, ajf, sj);
  score_kernel<<<2048, 256, 0, stream>>>(ci, si, sj, abf, attp);
  attn_kernel<<<3280, 256, 0, stream>>>(h, attp, Whp, d_out);
}

// Round 11
// 157.182 us; speedup vs baseline: 1.0491x; 1.0491x over previous
//
#include <hip/hip_runtime.h>
#include <hip/hip_bf16.h>

typedef unsigned short u16;
typedef unsigned int u32;
typedef __attribute__((ext_vector_type(8))) __bf16 bf16x8;
typedef __attribute__((ext_vector_type(4))) __bf16 bf16x4;
typedef __attribute__((ext_vector_type(4))) float f32x4;

#define KCTX 32
#define INF_ 608
#define HID_ 384
#define NBOX 16384

// ws layout (bytes).
#define WH_OFF  19922944              // Wh  [16384,384] bf16 = 12,582,912
#define BT_OFF  32505856              // Bt  [384,608]  bf16 =    466,944
#define V_OFF   32972800              // v   [608] f32        =      2,432
#define SI_OFF  32975232              // si  [16384] f32      =     65,536
#define SJ_OFF  33040768              // sj  [16384] f32      =     65,536
#define AJF_OFF 33106304              // ajf [384] f32        =      1,536
#define ABF_OFF 33107840              // abf [1] f32

__device__ __forceinline__ float bfu(u16 u)  { return __uint_as_float(((u32)u) << 16); }
__device__ __forceinline__ float bflo(u32 u) { return __uint_as_float(u << 16); }
__device__ __forceinline__ float bfhi(u32 u) { return __uint_as_float(u & 0xffff0000u); }
__device__ __forceinline__ u16 f2bf(float x) {            // round-to-nearest-even
  u32 u = __float_as_uint(x);
  return (u16)((u + 0x7fffu + ((u >> 16) & 1u)) >> 16);
}
__device__ __forceinline__ void async_ld16(const void* g, void* l) {
  __builtin_amdgcn_global_load_lds(
      (const __attribute__((address_space(1))) u32*)g,
      (__attribute__((address_space(3))) u32*)l, 16, 0, 0);
}

// ---- per-wave runtime dtype detection (wave-uniform, L2-hot; validated r2-r10) ----
__device__ __forceinline__ int detect_f32(const u32* hw) {
  const u32 w = hw[threadIdx.x & 63];
  const int e = (int)((w >> 7) & 0xffu);
  const unsigned long long mb = __ballot(e > 134 || e < 100);
  return __popcll(mb) >= 16;
}
__device__ __forceinline__ int detect_i64(const int* ci) {
  const int hi = ci[2 * (threadIdx.x & 63) + 1];
  const unsigned long long mz = __ballot(hi == 0 || hi == -1);
  return __popcll(mz) >= 48;
}

// ---- prep: Bt = bf16(W_j^T), v = W_i@a_i, ajf/abf fp32, zero sj ----
__global__ __launch_bounds__(256) void prep_kernel(
    const void* __restrict__ h, const void* __restrict__ Wi,
    const void* __restrict__ Wj, const void* __restrict__ ai,
    const void* __restrict__ aj, const void* __restrict__ ab,
    u16* __restrict__ Bt, float* __restrict__ v, float* __restrict__ sj,
    float* __restrict__ ajf, float* __restrict__ abf) {
  __shared__ u16 tile[64][65];
  const int f32m = detect_f32((const u32*)h);
  const int bid = blockIdx.x, tid = threadIdx.x;
  if (bid < 60) {                                  // transpose: 10(f) x 6(h) tiles
    const int ft = bid / 6, ht = bid - ft * 6;
    const int f0 = ft * 64, h0 = ht * 64;
    const int ln = tid & 63, fg = tid >> 6;
#pragma unroll
    for (int rr = 0; rr < 16; ++rr) {
      const int fl = fg * 16 + rr;
      const int f = f0 + fl;
      if (f < INF_)
        tile[fl][ln] = f32m ? f2bf(((const float*)Wj)[(size_t)f * HID_ + h0 + ln])
                            : ((const u16*)Wj)[(size_t)f * HID_ + h0 + ln];
    }
    __syncthreads();
#pragma unroll
    for (int rr = 0; rr < 16; ++rr) {
      const int hl = fg * 16 + rr;
      const int f = f0 + ln;
      if (f < INF_) Bt[(size_t)(h0 + hl) * INF_ + f] = tile[ln][hl];
    }
  } else if (bid < 98) {                           // v: 16-lane group per row
    const int t = (bid - 60) * 16 + (tid >> 4);
    const int sl = tid & 15;
    if (t < INF_) {
      float s = 0.f;
      if (f32m) {
        const float4* wi = (const float4*)((const float*)Wi + (size_t)t * HID_);
        const float4* a4 = (const float4*)ai;
        for (int c = sl; c < 96; c += 16) {
          float4 x = wi[c], y = a4[c];
          s += x.x * y.x + x.y * y.y + x.z * y.z + x.w * y.w;
        }
      } else {
        const uint4* wi = (const uint4*)((const u16*)Wi + (size_t)t * HID_);
        const uint4* a4 = (const uint4*)ai;
        for (int c = sl; c < 48; c += 16) {
          uint4 x = wi[c], y = a4[c];
          s += bflo(x.x) * bflo(y.x) + bfhi(x.x) * bfhi(y.x)
             + bflo(x.y) * bflo(y.y) + bfhi(x.y) * bfhi(y.y)
             + bflo(x.z) * bflo(y.z) + bfhi(x.z) * bfhi(y.z)
             + bflo(x.w) * bflo(y.w) + bfhi(x.w) * bfhi(y.w);
        }
      }
      s += __shfl_xor(s, 1); s += __shfl_xor(s, 2);
      s += __shfl_xor(s, 4); s += __shfl_xor(s, 8);
      if (sl == 0) v[t] = s;
    }
  } else {                                         // zero sj, build ajf/abf
#pragma unroll 8
    for (int j = 0; j < 64; ++j) sj[j * 256 + tid] = 0.f;
    for (int j = tid; j < HID_; j += 256)
      ajf[j] = f32m ? ((const float*)aj)[j] : bfu(((const u16*)aj)[j]);
    if (tid == 0)
      abf[0] = f32m ? ((const float*)ab)[0] : bfu(((const u16*)ab)[0]);
  }
}

// ---- gemm_fused: 32 rows A-resident (h read once, si fused), Bt streamed
// via global_load_lds, 4 waves x (m=32,n=96) MFMA, fused sj epilogue ----
__global__ __launch_bounds__(256) void gemm_fused(
    const void* __restrict__ A, const u16* __restrict__ Bt,
    const float* __restrict__ v, u16* __restrict__ C,
    float* __restrict__ si, const float* __restrict__ ajf,
    float* __restrict__ sj) {
  __shared__ __align__(16) u16 As[32][612];
  __shared__ __align__(16) u16 Bs[12288];          // [384][32]
  const int f32m = detect_f32((const u32*)A);
  const int tid  = threadIdx.x;
  const int lane = tid & 63;
  const int wv   = tid >> 6;
  const int row0 = blockIdx.x * 32;
  const char* Btb = (const char*)Bt;

#pragma unroll
  for (int i = 0; i < 6; ++i) {
    const int c = tid + i * 256;
    async_ld16(Btb + (size_t)(c >> 2) * 1216 + (c & 3) * 16, (char*)Bs + c * 16);
  }

  {
    const int g = tid >> 3, sub = tid & 7;
    float s = 0.f;
    const float4* v4 = (const float4*)v;
    if (f32m) {
      const float4* hr = (const float4*)((const float*)A + (size_t)(row0 + g) * INF_);
#pragma unroll
      for (int k = 0; k < 19; ++k) {
        const int c4 = sub + 8 * k;
        float4 x = hr[c4];
        ushort4 sv;
        sv.x = f2bf(x.x); sv.y = f2bf(x.y); sv.z = f2bf(x.z); sv.w = f2bf(x.w);
        *(ushort4*)&As[g][c4 * 4] = sv;
        float4 w = v4[c4];
        s += x.x * w.x + x.y * w.y + x.z * w.z + x.w * w.w;
      }
    } else {
      const uint4* hr = (const uint4*)((const u16*)A + (size_t)(row0 + g) * INF_);
      for (int k = 0; k < 10; ++k) {
        const int c8 = sub + 8 * k;
        if (c8 < 76) {
          uint4 x = hr[c8];
          *(ushort4*)&As[g][c8 * 8]     = *(ushort4*)&x.x;
          *(ushort4*)&As[g][c8 * 8 + 4] = *(ushort4*)&x.z;
          float4 w0 = v4[2 * c8], w1 = v4[2 * c8 + 1];
          s += bflo(x.x) * w0.x + bfhi(x.x) * w0.y + bflo(x.y) * w0.z + bfhi(x.y) * w0.w
             + bflo(x.z) * w1.x + bfhi(x.z) * w1.y + bflo(x.w) * w1.z + bfhi(x.w) * w1.w;
        }
      }
    }
    s += __shfl_xor(s, 1); s += __shfl_xor(s, 2); s += __shfl_xor(s, 4);
    if (sub == 0) si[row0 + g] = s;
  }

  f32x4 acc[2][6];
#pragma unroll
  for (int i = 0; i < 2; ++i)
#pragma unroll
    for (int j = 0; j < 6; ++j) acc[i][j] = (f32x4){0.f, 0.f, 0.f, 0.f};

  const int lm = lane & 15, q = lane >> 4;
  const int n0 = wv * 96;

  for (int kt = 0; kt < 19; ++kt) {
    __syncthreads();
    bf16x8 af[2], bfr[6];
#pragma unroll
    for (int im = 0; im < 2; ++im) {
      const int r = im * 16 + lm;
      bf16x4 lo = *(const bf16x4*)&As[r][kt * 32 + q * 8];
      bf16x4 hi = *(const bf16x4*)&As[r][kt * 32 + q * 8 + 4];
      af[im] = __builtin_shufflevector(lo, hi, 0, 1, 2, 3, 4, 5, 6, 7);
    }
#pragma unroll
    for (int in = 0; in < 6; ++in)
      bfr[in] = *(const bf16x8*)&Bs[(n0 + in * 16 + lm) * 32 + q * 8];
#pragma unroll
    for (int im = 0; im < 2; ++im)
#pragma unroll
      for (int in = 0; in < 6; ++in)
        acc[im][in] = __builtin_amdgcn_mfma_f32_16x16x32_bf16(
            af[im], bfr[in], acc[im][in], 0, 0, 0);
    __syncthreads();
    if (kt < 18) {
      const size_t kb = (size_t)(kt + 1) * 64;
#pragma unroll
      for (int i = 0; i < 6; ++i) {
        const int c = tid + i * 256;
        async_ld16(Btb + (size_t)(c >> 2) * 1216 + kb + (c & 3) * 16, (char*)Bs + c * 16);
      }
    }
  }

#pragma unroll
  for (int im = 0; im < 2; ++im)
#pragma unroll
    for (int in = 0; in < 6; ++in) {
      const int colg = n0 + in * 16 + lm;
#pragma unroll
      for (int r = 0; r < 4; ++r) {
        const int rowg = row0 + im * 16 + q * 4 + r;
        C[(size_t)rowg * HID_ + colg] = f2bf(acc[im][in][r]);
      }
    }
  float ajv[6];
#pragma unroll
  for (int in = 0; in < 6; ++in) ajv[in] = ajf[n0 + in * 16 + lm];
#pragma unroll
  for (int im = 0; im < 2; ++im)
#pragma unroll
    for (int r = 0; r < 4; ++r) {
      float p = acc[im][0][r] * ajv[0] + acc[im][1][r] * ajv[1]
              + acc[im][2][r] * ajv[2] + acc[im][3][r] * ajv[3]
              + acc[im][4][r] * ajv[4] + acc[im][5][r] * ajv[5];
      p += __shfl_xor(p, 1); p += __shfl_xor(p, 2);
      p += __shfl_xor(p, 4); p += __shfl_xor(p, 8);
      if (lm == 0) atomicAdd(&sj[row0 + im * 16 + q * 4 + r], p);
    }
}

// ---- attn: 5 rows/block, compacted valid-k gather, 8-deep batching (r9) ----
__global__ __launch_bounds__(256) void attn_kernel(
    const void* __restrict__ h, const int* __restrict__ ci,
    const float* __restrict__ si, const float* __restrict__ sj,
    const float* __restrict__ abf, const u16* __restrict__ Wh,
    void* __restrict__ out) {
  __shared__ float2 ai_c[5][32];     // .x = att weight, .y = idx bits
  __shared__ int cnt_s[5];
  const int f32m = detect_f32((const u32*)h);
  const int i64  = detect_i64(ci);
  const int tid = threadIdx.x;
  const int n0 = blockIdx.x * 5;

  if (tid < 160) {
    const int r = tid >> 5, k = tid & 31;
    const int n = n0 + r;
    if (n < NBOX) {
      const size_t t = (size_t)n * KCTX + k;
      int idx;
      if (i64) { int lo = ci[2 * t], hi2 = ci[2 * t + 1]; idx = (hi2 < 0) ? -1 : lo; }
      else     { idx = ci[t]; }
      const bool valid = idx >= 0;
      const float sjv = valid ? sj[idx] : 0.f;
      float raw = si[n] + sjv + abf[0];
      float lr = raw > 0.f ? raw : 0.2f * raw;
      float s = valid ? lr : -9e15f;
      float m = s;
#pragma unroll
      for (int o = 16; o; o >>= 1) m = fmaxf(m, __shfl_xor(m, o, 32));
      float p = __expf(s - m);
      float d = p;
#pragma unroll
      for (int o = 16; o; o >>= 1) d += __shfl_xor(d, o, 32);
      const unsigned long long bm = __ballot(valid);
      const u32 m32 = (u32)(bm >> (tid & 32));
      const int cnt = __popc(m32);
      const int r8 = (cnt + 7) & ~7;
      if (valid) {
        const int pf = __popc(m32 & ((1u << k) - 1u));
        ai_c[r][pf] = (float2){p / d, __int_as_float(idx)};
      }
      if (k >= cnt && k < r8) ai_c[r][k] = (float2){0.f, 0.f};
      if (k == 0) cnt_s[r] = r8;
    } else if ((tid & 31) == 0) {
      cnt_s[r] = 0;
    }
  }
  __syncthreads();

  if (tid < 240) {
    const int r = tid / 48, c = tid - r * 48;
    const int n = n0 + r;
    if (n < NBOX) {
      const int K8 = cnt_s[r];
      float a0 = 0, a1 = 0, a2 = 0, a3 = 0, a4 = 0, a5 = 0, a6 = 0, a7 = 0;
      for (int kb = 0; kb < K8; kb += 8) {
        uint4 q[8]; float ww[8];
#pragma unroll
        for (int u = 0; u < 8; ++u) {              // 8 loads in flight
          const float2 e = ai_c[r][kb + u];
          ww[u] = e.x;
          const int j = __float_as_int(e.y);
          q[u] = ((const uint4*)(Wh + (u32)j * HID_))[c];
        }
#pragma unroll
        for (int u = 0; u < 8; ++u) {
          const float w = ww[u];
          a0 += w * bflo(q[u].x); a1 += w * bfhi(q[u].x);
          a2 += w * bflo(q[u].y); a3 += w * bfhi(q[u].y);
          a4 += w * bflo(q[u].z); a5 += w * bfhi(q[u].z);
          a6 += w * bflo(q[u].w); a7 += w * bfhi(q[u].w);
        }
      }
      if (f32m) {
        float4* o4 = (float4*)out + (size_t)n * 96 + c * 2;
        o4[0] = (float4){a0, a1, a2, a3};
        o4[1] = (float4){a4, a5, a6, a7};
      } else {
        uint4 o;
        o.x = (u32)f2bf(a0) | ((u32)f2bf(a1) << 16);
        o.y = (u32)f2bf(a2) | ((u32)f2bf(a3) << 16);
        o.z = (u32)f2bf(a4) | ((u32)f2bf(a5) << 16);
        o.w = (u32)f2bf(a6) | ((u32)f2bf(a7) << 16);
        ((uint4*)out)[(size_t)n * 48 + c] = o;
      }
    }
  }
}

extern "C" void kernel_launch(void* const* d_in, const int* in_sizes, int n_in,
                              void* d_out, int out_size, void* d_ws, size_t ws_size,
                              hipStream_t stream) {
  const void* h  = d_in[0];
  const int*  ci = (const int*)d_in[1];
  const void* Wi = d_in[2];
  const void* Wj = d_in[3];
  const void* ai = d_in[4];
  const void* aj = d_in[5];
  const void* ab = d_in[6];

  char* ws = (char*)d_ws;
  u16*   Wh  = (u16*)(ws + WH_OFF);
  u16*   Bt  = (u16*)(ws + BT_OFF);
  float* v   = (float*)(ws + V_OFF);
  float* si  = (float*)(ws + SI_OFF);
  float* sj  = (float*)(ws + SJ_OFF);
  float* ajf = (float*)(ws + AJF_OFF);
  float* abf = (float*)(ws + ABF_OFF);

  prep_kernel<<<99, 256, 0, stream>>>(h, Wi, Wj, ai, aj, ab, Bt, v, sj, ajf, abf);
  gemm_fused<<<512, 256, 0, stream>>>(h, Bt, v, Wh, si, ajf, sj);
  attn_kernel<<<3277, 256, 0, stream>>>(h, ci, si, sj, abf, Wh, d_out);
}